// Round 3
// baseline (485.893 us; speedup 1.0000x reference)
//
#include <hip/hip_runtime.h>
#include <stdint.h>

// BiRealConv2d: y = conv2d(sign(x), scale[o]*sign(w)), NCHW, 3x3, pad 1.
// Exact integer XNOR-popcount formulation.
// R3: conv: __launch_bounds__(256,4) for 128-VGPR budget (R2's VGPR=32 meant
//     taps were never resident -> 2.3x VALU bloat); weights staged in LDS,
//     ds_read_b128 w/ immediate offsets; border corrections moved to a tiny
//     cleanup kernel so the hot loop is pure xor/popcount.
//     pack: halo-zeroing fused (memset dispatch removed).

#define HH 112
#define WW 112
#define CC 128
#define OO 128
#define NN 32
#define HP 114   // padded
#define WP 114

// ---------------- pass 1: pack sign(x); also zeroes the halo ----------------------
// grid (2, HP, NN), block 256 = 4 waves; lane = w, grp = 32-channel group.
__global__ __launch_bounds__(256) void pack_x_kernel(const float* __restrict__ x,
                                                     uint32_t* __restrict__ xb32) {
  int t = threadIdx.x;
  int lane = t & 63;
  int grp = t >> 6;                 // channels [grp*32, grp*32+32)
  int wseg = blockIdx.x * 64 + lane;  // 0..127
  int hp = blockIdx.y;                // padded row 0..113
  int n = blockIdx.z;
  size_t rowbase = ((size_t)n * HP + hp) * WP;
  if (hp == 0 || hp == HP - 1) {      // top/bottom halo rows: zero all 114 pixels
    if (wseg < WP) xb32[(rowbase + wseg) * 4 + grp] = 0u;
    return;
  }
  int h = hp - 1;
  if (wseg < WW) {
    const float* xp = x + (((size_t)n * CC + grp * 32) * HH + h) * WW + wseg;
    uint32_t mm = 0u;
#pragma unroll
    for (int b = 0; b < 32; b++) {
      float v = xp[(size_t)b * (HH * WW)];
      mm |= (v > 0.0f) ? (1u << b) : 0u;   // bit=1 -> +1, bit=0 -> -1
    }
    xb32[(rowbase + (wseg + 1)) * 4 + grp] = mm;
  } else if (wseg == WW) {            // right halo (w_pad = 113)
    xb32[(rowbase + (WP - 1)) * 4 + grp] = 0u;
  } else if (wseg == WW + 1) {        // left halo (w_pad = 0)
    xb32[(rowbase + 0) * 4 + grp] = 0u;
  }
}

// ---------------- pass 0: weight bitmasks + fused epilogue constants --------------
// f2i[o] = scale*c2_interior, s2[o] = 2*scale, fix[o][pat] = scale*(c2[pat]-c2_int)
__global__ __launch_bounds__(256) void prep_w_kernel(const float* __restrict__ wt,
                                                     uint64_t* __restrict__ wbits,
                                                     float* __restrict__ s2,
                                                     float* __restrict__ f2i,
                                                     float* __restrict__ fix) {
  int o = blockIdx.x;
  const float* wo = wt + (size_t)o * (CC * 9);
  __shared__ unsigned int bits[9][4];
  __shared__ float red[256];
  int t = threadIdx.x;
  if (t < 36) ((unsigned int*)bits)[t] = 0u;
  __syncthreads();
  float s = 0.0f;
  for (int idx = t; idx < CC * 9; idx += 256) {
    float v = wo[idx];
    s += fabsf(v);
    int ci = idx / 9, tap = idx % 9;      // OIHW: tap = kh*3+kw
    if (v > 0.0f) atomicOr(&bits[tap][ci >> 5], 1u << (ci & 31));
  }
  red[t] = s;
  __syncthreads();
  for (int st = 128; st > 0; st >>= 1) {
    if (t < st) red[t] += red[t + st];
    __syncthreads();
  }
  if (t == 0) {
    float sc = red[0] * (1.0f / 1152.0f);
    int c[9];
#pragma unroll
    for (int tap = 0; tap < 9; tap++) {
      uint64_t lo = (uint64_t)bits[tap][0] | ((uint64_t)bits[tap][1] << 32);
      uint64_t hi = (uint64_t)bits[tap][2] | ((uint64_t)bits[tap][3] << 32);
      wbits[o * 18 + tap * 2]     = lo;
      wbits[o * 18 + tap * 2 + 1] = hi;
      c[tap] = 128 - 2 * (__builtin_popcountll(lo) + __builtin_popcountll(hi));
    }
    int c2[9];
    for (int ph = 0; ph < 3; ph++)
      for (int pw = 0; pw < 3; pw++) {
        int sum = 0;
        for (int tap = 0; tap < 9; tap++) {
          int kh = tap / 3, kw = tap % 3;
          bool inv = (ph == 0 && kh == 0) || (ph == 2 && kh == 2) ||
                     (pw == 0 && kw == 0) || (pw == 2 && kw == 2);
          if (inv) sum += c[tap];     // spurious halo term
        }
        c2[ph * 3 + pw] = 1152 - sum;
      }
    s2[o]  = 2.0f * sc;
    f2i[o] = sc * (float)c2[4];
    for (int p = 0; p < 9; p++) fix[o * 9 + p] = sc * (float)(c2[p] - c2[4]);
  }
}

// ---------------- pass 2: XNOR-popcount conv (interior form) ----------------------
__global__ __launch_bounds__(256, 4) void conv_kernel(const uint64_t* __restrict__ xb,
                                                      const uint64_t* __restrict__ wbits,
                                                      const float* __restrict__ s2,
                                                      const float* __restrict__ f2i,
                                                      float* __restrict__ out) {
  __shared__ uint64_t lw[OO * 18];   // 18,432 B: lw[o*18 + word]
  int t = threadIdx.x;
  for (int i = t; i < OO * 18; i += 256) lw[i] = wbits[i];

  int og = __builtin_amdgcn_readfirstlane(t >> 6);  // wave-uniform o-group
  int wl = t & 63;
  int w = blockIdx.x * 64 + wl;
  int h = blockIdx.y;
  int n = blockIdx.z;
  bool valid = (w < WW);
  __syncthreads();
  if (!valid) return;

  // 9 taps x 128 bits = 18 u64, loaded once, resident (128-VGPR budget).
  const uint64_t* xbase = xb + (((size_t)n * HP + h) * WP + w) * 2;
  uint64_t xv[18];
#pragma unroll
  for (int dh = 0; dh < 3; dh++)
#pragma unroll
    for (int dw = 0; dw < 3; dw++) {
      const ulonglong2 v = *(const ulonglong2*)(xbase + ((size_t)dh * WP + dw) * 2);
      xv[(dh * 3 + dw) * 2]     = v.x;
      xv[(dh * 3 + dw) * 2 + 1] = v.y;
    }
#pragma unroll
  for (int i = 0; i < 18; i++) asm volatile("" : "+v"(xv[i]));

  size_t obase = (((size_t)(n * OO + og * 32)) * HH + h) * WW + w;
#pragma unroll 2
  for (int j = 0; j < 32; j++) {
    int o = (og << 5) + j;                         // wave-uniform -> s_load consts
    const uint64_t* wp = lw + o * 18;              // LDS, broadcast reads, imm offs
    int pc = 0;
#pragma unroll
    for (int tap = 0; tap < 18; tap++)
      pc += __builtin_popcountll(xv[tap] ^ wp[tap]);
    out[obase] = f2i[o] - s2[o] * (float)pc;       // interior form
    obase += (size_t)HH * WW;
  }
}

// ---------------- pass 3: border fixup (3.5% of pixels, RMW) ----------------------
__global__ __launch_bounds__(256) void fix_border_kernel(const float* __restrict__ fix,
                                                         float* __restrict__ out) {
  int idx = blockIdx.x * 256 + threadIdx.x;   // o = idx>>9, bi = idx&511
  int o = idx >> 9;
  int bi = idx & 511;
  int n = blockIdx.y;
  if (bi >= 444) return;
  int h, w;
  if (bi < 112)      { h = 0;            w = bi; }
  else if (bi < 224) { h = HH - 1;       w = bi - 112; }
  else if (bi < 334) { h = bi - 224 + 1; w = 0; }
  else               { h = bi - 334 + 1; w = WW - 1; }
  int ph = (h == 0) ? 0 : ((h == HH - 1) ? 2 : 1);
  int pw = (w == 0) ? 0 : ((w == WW - 1) ? 2 : 1);
  size_t oi = (((size_t)n * OO + o) * HH + h) * WW + w;
  out[oi] += fix[o * 9 + ph * 3 + pw];
}

extern "C" void kernel_launch(void* const* d_in, const int* in_sizes, int n_in,
                              void* d_out, int out_size, void* d_ws, size_t ws_size,
                              hipStream_t stream) {
  const float* x  = (const float*)d_in[0];
  const float* wt = (const float*)d_in[1];
  float* out = (float*)d_out;

  char* ws = (char*)d_ws;
  size_t xb_elems = (size_t)NN * HP * WP * 2;       // u64 (6.65 MB)
  uint64_t* xb    = (uint64_t*)ws;
  size_t off = xb_elems * 8;
  uint64_t* wbits = (uint64_t*)(ws + off); off += (size_t)OO * 18 * 8;
  float* s2       = (float*)(ws + off);    off += (size_t)OO * 4;
  float* f2i      = (float*)(ws + off);    off += (size_t)OO * 4;
  float* fix      = (float*)(ws + off);    off += (size_t)OO * 9 * 4;

  hipLaunchKernelGGL(pack_x_kernel, dim3(2, HP, NN), dim3(256), 0, stream,
                     x, (uint32_t*)xb);
  hipLaunchKernelGGL(prep_w_kernel, dim3(OO), dim3(256), 0, stream,
                     wt, wbits, s2, f2i, fix);
  hipLaunchKernelGGL(conv_kernel, dim3(2, HH, NN), dim3(256), 0, stream,
                     xb, wbits, s2, f2i, out);
  hipLaunchKernelGGL(fix_border_kernel, dim3(256, NN), dim3(256), 0, stream,
                     fix, out);
}